// Round 5
// baseline (102.290 us; speedup 1.0000x reference)
//
#include <hip/hip_runtime.h>

// RelationAttention: B=8, S=512, H=256, A=64
//   scores[b,i,j] = sum_a v[a]*tanh(ta[b,i,a]+ja[b,j,a]+b[a]); out = softmax_j
//
// tanh(x) = 1 - 2/(1+e^{2x});  e^{2(ta+b+ja)} = Et * Ej with
//   Et = exp(2*(ta+b))  stored (B,S,A)
//   Ej = exp(2*ja)      stored interleaved (B, A/4, S, 4)
// score = sum(v) + sum_a (-2*v[a]) * rcp(1 + Et*Ej)
//
// R4 lesson: broadcast ds_read_b128 still costs ~12 cyc of per-CU DS pipe.
// This round amortizes every LDS read over more FMAs/terms:
//   stage1: 2 rows/lane x 4 cols/wave -> DS instr x0.6, all b128 conflict-free
//   stage2: 2 j/thread -> T/V LDS reads amortized over 128 terms, waves/CU
//           halved; DS (~5.8us/CU) now hidden under the rcp VALU floor (~10us)

#define B_ 8
#define S_ 512
#define H_ 256
#define A_ 64

// ---------------- Stage 1: projections + exp precompute ----------------
// grid = 256: rb = idx&31 (128-row block), cb = idx>>5 (16 combined cols).
// idx%8 == rb%8 -> all 8 cb-blocks of one rb share an XCD (rh L2-resident).
// block = 256 threads (4 waves); lane = 2 rows (lane, lane+64); wave = 4 cols.
__global__ __launch_bounds__(256) void rel_stage1(
    const float* __restrict__ rh, const float* __restrict__ wta,
    const float* __restrict__ wja, const float* __restrict__ bias,
    float* __restrict__ ta2e, float* __restrict__ ej) {
  __shared__ float rhs[128][65];              // 32.5 KB; b128 read 2-way = free
  __shared__ __align__(16) float ws[16][68];  // 4.25 KB
  const int t = threadIdx.x;
  const int rb = blockIdx.x & 31;
  const int cb = blockIdx.x >> 5;
  const int row0 = rb << 7;
  const int lane = t & 63;
  const int cg0 = cb << 4;  // block col base; [cg0,cg0+16) never straddles A_
  const int cl = __builtin_amdgcn_readfirstlane((t >> 6) << 2);  // wave col
  const float* wsrc = (cg0 < A_) ? (wta + (size_t)cg0 * H_)
                                 : (wja + (size_t)(cg0 - A_) * H_);
  const int sr = t >> 4, sq = t & 15;

  float4 acc0 = {0.f, 0.f, 0.f, 0.f};  // row lane      x cols cl..cl+3
  float4 acc1 = {0.f, 0.f, 0.f, 0.f};  // row lane+64   x cols cl..cl+3
  for (int kt = 0; kt < H_; kt += 64) {
    if (kt) __syncthreads();  // protect previous tile's readers
#pragma unroll
    for (int i = 0; i < 8; ++i) {  // rh tile: 128 rows x 64 k, coalesced
      const int fid = t + (i << 8);
      const int r = fid >> 4, kq = fid & 15;
      *(float4*)&rhs[r][kq << 2] =
          *(const float4*)&rh[(size_t)(row0 + r) * H_ + kt + (kq << 2)];
    }
    *(float4*)&ws[sr][sq << 2] =  // w tile: 16 cols x 64 k
        *(const float4*)&wsrc[(size_t)sr * H_ + kt + (sq << 2)];
    __syncthreads();
#pragma unroll 4
    for (int k4 = 0; k4 < 16; ++k4) {
      const int k = k4 << 2;
      const float4 x0 = *(const float4*)&rhs[lane][k];       // b128, 2-way
      const float4 x1 = *(const float4*)&rhs[lane + 64][k];  // b128, 2-way
      const float4 w0 = *(const float4*)&ws[cl + 0][k];      // broadcast b128
      const float4 w1 = *(const float4*)&ws[cl + 1][k];
      const float4 w2 = *(const float4*)&ws[cl + 2][k];
      const float4 w3 = *(const float4*)&ws[cl + 3][k];
      acc0.x += x0.x * w0.x + x0.y * w0.y + x0.z * w0.z + x0.w * w0.w;
      acc0.y += x0.x * w1.x + x0.y * w1.y + x0.z * w1.z + x0.w * w1.w;
      acc0.z += x0.x * w2.x + x0.y * w2.y + x0.z * w2.z + x0.w * w2.w;
      acc0.w += x0.x * w3.x + x0.y * w3.y + x0.z * w3.z + x0.w * w3.w;
      acc1.x += x1.x * w0.x + x1.y * w0.y + x1.z * w0.z + x1.w * w0.w;
      acc1.y += x1.x * w1.x + x1.y * w1.y + x1.z * w1.z + x1.w * w1.w;
      acc1.z += x1.x * w2.x + x1.y * w2.y + x1.z * w2.z + x1.w * w2.w;
      acc1.w += x1.x * w3.x + x1.y * w3.y + x1.z * w3.z + x1.w * w3.w;
    }
  }

  const int cg = cg0 + cl;  // combined col 0..127, wave-uniform
  if (cg < A_) {            // Et = exp(2*(ta+bias)), layout (B,S,A)
    const float b0 = bias[cg + 0], b1 = bias[cg + 1];
    const float b2 = bias[cg + 2], b3 = bias[cg + 3];
    float4 e;
    e.x = __expf(2.f * (acc0.x + b0));
    e.y = __expf(2.f * (acc0.y + b1));
    e.z = __expf(2.f * (acc0.z + b2));
    e.w = __expf(2.f * (acc0.w + b3));
    *(float4*)&ta2e[(size_t)(row0 + lane) * A_ + cg] = e;
    e.x = __expf(2.f * (acc1.x + b0));
    e.y = __expf(2.f * (acc1.y + b1));
    e.z = __expf(2.f * (acc1.z + b2));
    e.w = __expf(2.f * (acc1.w + b3));
    *(float4*)&ta2e[(size_t)(row0 + lane + 64) * A_ + cg] = e;
  } else {  // Ej = exp(2*ja), layout (B, A/4, S, 4)
    const int g = (cg - A_) >> 2;
#pragma unroll
    for (int rr = 0; rr < 2; ++rr) {
      const int row = row0 + lane + (rr << 6);
      const int bidx = row >> 9;
      const int s = row & (S_ - 1);
      const float4 a = rr ? acc1 : acc0;
      float4 e;
      e.x = __expf(2.f * a.x);
      e.y = __expf(2.f * a.y);
      e.z = __expf(2.f * a.z);
      e.w = __expf(2.f * a.w);
      *(float4*)&ej[(((size_t)bidx * 16 + g) * S_ + s) << 2] = e;
    }
  }
}

// ---------------- Stage 2: rcp-reduce + softmax ----------------
// grid = 512 blocks (8 query rows each), block = 256 threads, 2 j per thread
// (j = t and t+256). Per g: 2 coalesced float4 Ej loads amortize the 9 LDS
// b128 broadcasts over 128 terms -> DS ~5.8us/CU hidden under rcp VALU floor.
__global__ __launch_bounds__(256) void rel_stage2(
    const float* __restrict__ ta2e, const float* __restrict__ ej,
    const float* __restrict__ v, float* __restrict__ out) {
  __shared__ __align__(16) float tai[8][A_];  // 2 KB
  __shared__ __align__(16) float vm[A_];      // -2*v
  __shared__ float red[8][4];
  const int t = threadIdx.x;
  const int row0 = blockIdx.x << 3;  // global row = b*S + i
  const int bidx = row0 >> 9;
  *(float2*)&tai[0][0 + (t << 1) - ((t >> 5) << 6) + ((t >> 5) << 6)] =
      *(const float2*)&ta2e[(size_t)row0 * A_ + (t << 1)];  // 512 floats
  if (t < A_) vm[t] = -2.f * v[t];
  __syncthreads();

  float vsum = 0.f;
#pragma unroll
  for (int a = 0; a < A_; a += 4) {
    const float4 x = *(const float4*)&vm[a];
    vsum += x.x + x.y + x.z + x.w;
  }
  vsum *= -0.5f;  // sum(v)

  float acc0[8] = {0.f, 0.f, 0.f, 0.f, 0.f, 0.f, 0.f, 0.f};  // j0 = t
  float acc1[8] = {0.f, 0.f, 0.f, 0.f, 0.f, 0.f, 0.f, 0.f};  // j1 = t+256
  const float* ejb = ej + (((size_t)bidx * 16) * S_ << 2) + (t << 2);
#pragma unroll 2
  for (int g = 0; g < 16; ++g) {
    const float4 E0 = *(const float4*)(ejb + ((size_t)g * S_ << 2));
    const float4 E1 = *(const float4*)(ejb + ((size_t)g * S_ << 2) + 1024);
    const float4 V = *(const float4*)&vm[g << 2];
#pragma unroll
    for (int r = 0; r < 8; ++r) {
      const float4 T = *(const float4*)&tai[r][g << 2];
      acc0[r] += V.x * __builtin_amdgcn_rcpf(__builtin_fmaf(T.x, E0.x, 1.f))
               + V.y * __builtin_amdgcn_rcpf(__builtin_fmaf(T.y, E0.y, 1.f))
               + V.z * __builtin_amdgcn_rcpf(__builtin_fmaf(T.z, E0.z, 1.f))
               + V.w * __builtin_amdgcn_rcpf(__builtin_fmaf(T.w, E0.w, 1.f));
      acc1[r] += V.x * __builtin_amdgcn_rcpf(__builtin_fmaf(T.x, E1.x, 1.f))
               + V.y * __builtin_amdgcn_rcpf(__builtin_fmaf(T.y, E1.y, 1.f))
               + V.z * __builtin_amdgcn_rcpf(__builtin_fmaf(T.z, E1.z, 1.f))
               + V.w * __builtin_amdgcn_rcpf(__builtin_fmaf(T.w, E1.w, 1.f));
    }
  }

  // softmax over j (512 = 256 threads x 2), per row r
  const int lane = t & 63;
  const int wv = t >> 6;  // 4 waves
  float ex0[8], ex1[8], mx[8];
#pragma unroll
  for (int r = 0; r < 8; ++r) {
    const float s0 = vsum + acc0[r], s1 = vsum + acc1[r];
    ex0[r] = s0;
    ex1[r] = s1;
    float m = fmaxf(s0, s1);
#pragma unroll
    for (int off = 32; off; off >>= 1) m = fmaxf(m, __shfl_xor(m, off));
    if (lane == 0) red[r][wv] = m;
  }
  __syncthreads();
#pragma unroll
  for (int r = 0; r < 8; ++r)
    mx[r] = fmaxf(fmaxf(red[r][0], red[r][1]), fmaxf(red[r][2], red[r][3]));
  __syncthreads();
#pragma unroll
  for (int r = 0; r < 8; ++r) {
    ex0[r] = __expf(ex0[r] - mx[r]);
    ex1[r] = __expf(ex1[r] - mx[r]);
    float s = ex0[r] + ex1[r];
#pragma unroll
    for (int off = 32; off; off >>= 1) s += __shfl_xor(s, off);
    if (lane == 0) red[r][wv] = s;
  }
  __syncthreads();
#pragma unroll
  for (int r = 0; r < 8; ++r) {
    const float s = (red[r][0] + red[r][1]) + (red[r][2] + red[r][3]);
    const float inv = __builtin_amdgcn_rcpf(s);
    out[(size_t)(row0 + r) * S_ + t] = ex0[r] * inv;
    out[(size_t)(row0 + r) * S_ + t + 256] = ex1[r] * inv;
  }
}

extern "C" void kernel_launch(void* const* d_in, const int* in_sizes, int n_in,
                              void* d_out, int out_size, void* d_ws, size_t ws_size,
                              hipStream_t stream) {
  const float* rh   = (const float*)d_in[0];  // (B,S,H)
  const float* wta  = (const float*)d_in[1];  // (A,H)
  const float* wja  = (const float*)d_in[2];  // (A,H)
  const float* bias = (const float*)d_in[3];  // (1,1,1,A)
  const float* v    = (const float*)d_in[4];  // (1,A)
  float* out = (float*)d_out;                 // (B,S,S)

  float* ta2e = (float*)d_ws;                 // B*S*A floats = 1 MB
  float* ej   = ta2e + (size_t)B_ * S_ * A_;  // B*A*S floats = 1 MB

  rel_stage1<<<dim3(256), dim3(256), 0, stream>>>(rh, wta, wja, bias, ta2e, ej);
  rel_stage2<<<dim3((B_ * S_) / 8), dim3(256), 0, stream>>>(ta2e, ej, v, out);
}